// Round 8
// baseline (72.555 us; speedup 1.0000x reference)
//
#include <hip/hip_runtime.h>

#define N_CAND 8192
#define TILE   64                           // = wave width: 1 wave per block
#define NTILES (N_CAND / TILE)              // 128
#define NLIVE  (NTILES * (NTILES + 1) / 2)  // 8256 upper-triangle tiles

// Broadcast one lane's float to all lanes via SGPR (v_readlane_b32).
__device__ __forceinline__ float readlane_f(float x, int lane) {
    return __int_as_float(__builtin_amdgcn_readlane(__float_as_int(x), lane));
}

// ---------------------------------------------------------------------------
// R8: register-resident j-tile, ZERO memory ops in the inner loop.
// TILE=64 = wave width: lane l holds j-element (bj*64+l) in registers; the
// per-iteration j-value is block-uniform, so it's fetched with v_readlane
// (SGPR broadcast, 2cy, no LDS pipe / no lgkmcnt stall). R7 was latency-bound
// on the per-iter dependent ds_read_b64 (~74 cy/wave-iter vs the 24 cy
// trans floor). Full unroll gives immediate lane indices; 2 accumulators.
// Math identical to R7: sp = log2(1+2^dl) (|dl|<=~14), rcp(+inf)=0 masking.
// ---------------------------------------------------------------------------
__global__ __launch_bounds__(TILE) void ranknet_pairs_kernel(
    const float* __restrict__ logits,
    const int*   __restrict__ rankings,
    float*       __restrict__ partials)
{
    const int t = blockIdx.x;              // linear live-tile index
    // invert t = bj*(bj+1)/2 + bi, 0 <= bi <= bj < NTILES
    int bj = (int)((__builtin_sqrtf(8.0f * (float)t + 1.0f) - 1.0f) * 0.5f);
    while ((bj + 1) * (bj + 2) / 2 <= t) ++bj;   // guard fp rounding
    while (bj * (bj + 1) / 2 > t)       --bj;
    const int bi = t - bj * (bj + 1) / 2;

    const float LOG2E = 1.4426950408889634f;
    const float INF   = __builtin_inff();
    const int lane = threadIdx.x;

    // i-side per-lane values, j-side register copy (one element per lane)
    const float lis = logits[bi * TILE + lane] * LOG2E;
    const float ri  = (float)rankings[bi * TILE + lane];
    const float ljv = logits[bj * TILE + lane] * LOG2E;
    const float rjv = (float)rankings[bj * TILE + lane];

    float acc0 = 0.0f, acc1 = 0.0f;
    if (bi != bj) {
        // off-diagonal: i < j for every pair
        #pragma unroll
        for (int jj = 0; jj < TILE; jj += 2) {
            {
                const float lj = readlane_f(ljv, jj);
                const float rj = readlane_f(rjv, jj);
                const float dl = lj - lis;
                const float sp = __builtin_amdgcn_logf(1.0f + __builtin_amdgcn_exp2f(dl));
                const float rs = (rj > ri) ? (ri + rj) : INF;   // rcp(inf)=0 masks
                acc0 = fmaf(__builtin_amdgcn_rcpf(rs), sp, acc0);
            }
            {
                const float lj = readlane_f(ljv, jj + 1);
                const float rj = readlane_f(rjv, jj + 1);
                const float dl = lj - lis;
                const float sp = __builtin_amdgcn_logf(1.0f + __builtin_amdgcn_exp2f(dl));
                const float rs = (rj > ri) ? (ri + rj) : INF;
                acc1 = fmaf(__builtin_amdgcn_rcpf(rs), sp, acc1);
            }
        }
    } else {
        // diagonal tile: also require j > i  (jj > lane)
        #pragma unroll
        for (int jj = 0; jj < TILE; jj += 2) {
            {
                const float lj = readlane_f(ljv, jj);
                const float rj = readlane_f(rjv, jj);
                const float dl = lj - lis;
                const float sp = __builtin_amdgcn_logf(1.0f + __builtin_amdgcn_exp2f(dl));
                const bool act = (jj > lane) && (rj > ri);
                const float rs = act ? (ri + rj) : INF;
                acc0 = fmaf(__builtin_amdgcn_rcpf(rs), sp, acc0);
            }
            {
                const float lj = readlane_f(ljv, jj + 1);
                const float rj = readlane_f(rjv, jj + 1);
                const float dl = lj - lis;
                const float sp = __builtin_amdgcn_logf(1.0f + __builtin_amdgcn_exp2f(dl));
                const bool act = (jj + 1 > lane) && (rj > ri);
                const float rs = act ? (ri + rj) : INF;
                acc1 = fmaf(__builtin_amdgcn_rcpf(rs), sp, acc1);
            }
        }
    }

    // single-wave reduction — no LDS, no barrier
    float acc = acc0 + acc1;
    #pragma unroll
    for (int off = 32; off > 0; off >>= 1)
        acc += __shfl_down(acc, off, 64);
    if (lane == 0)
        partials[t] = acc;
}

// ---------------------------------------------------------------------------
// Pass 2: one 1024-thread block reduces the NLIVE partials; applies ln2/N.
// ---------------------------------------------------------------------------
__global__ __launch_bounds__(1024) void ranknet_reduce_kernel(
    const float* __restrict__ partials,
    float*       __restrict__ out)
{
    __shared__ float s_part[16];
    const int tid = threadIdx.x;

    float acc = 0.0f;
    for (int k = tid; k < NLIVE; k += 1024)
        acc += partials[k];

    #pragma unroll
    for (int off = 32; off > 0; off >>= 1)
        acc += __shfl_down(acc, off, 64);
    if ((tid & 63) == 0) s_part[tid >> 6] = acc;
    __syncthreads();
    if (tid == 0) {
        float s = 0.0f;
        #pragma unroll
        for (int w = 0; w < 16; ++w) s += s_part[w];
        const float LN2 = 0.6931471805599453f;
        out[0] = s * (LN2 / (float)N_CAND);
    }
}

extern "C" void kernel_launch(void* const* d_in, const int* in_sizes, int n_in,
                              void* d_out, int out_size, void* d_ws, size_t ws_size,
                              hipStream_t stream)
{
    const float* logits   = (const float*)d_in[0];
    const int*   rankings = (const int*)  d_in[1];
    float*       out      = (float*)d_out;
    float*       partials = (float*)d_ws;   // NLIVE floats = 33 KB

    ranknet_pairs_kernel<<<dim3(NLIVE), dim3(TILE), 0, stream>>>(logits, rankings, partials);
    ranknet_reduce_kernel<<<1, 1024, 0, stream>>>(partials, out);
}

// Round 9
// 71.645 us; speedup vs baseline: 1.0127x; 1.0127x over previous
//
#include <hip/hip_runtime.h>

#define N_CAND 8192
#define TILE   64                           // tile edge = wave width
#define NTILES (N_CAND / TILE)              // 128
#define NLIVE  (NTILES * (NTILES + 1) / 2)  // 8256 upper-triangle tiles
#define WPB    4                            // waves (tiles) per block
#define NBLK   (NLIVE / WPB)                // 2064 blocks, exact

// Broadcast one lane's float to all lanes via SGPR (v_readlane_b32).
__device__ __forceinline__ float readlane_f(float x, int lane) {
    return __int_as_float(__builtin_amdgcn_readlane(__float_as_int(x), lane));
}

// ---------------------------------------------------------------------------
// R9: one 64x64 tile per WAVE, 4 waves per block (2064 blocks), register-
// resident j-tile via v_readlane (no LDS, no barriers). 4 independent
// accumulator chains to hide the ~40cy sub->exp->add->log->rcp->fma latency.
// Math unchanged: logits pre-scaled by log2e, sp = log2(1+2^dl) (|dl|<=~14),
// masked pairs via rcp(+inf)=0. Issue model: ~40 cy per 64-pair wave-iter
// (3 trans x 8cy + ~7 VALU x 2cy) -> 8.6 us floor across 1024 SIMDs.
// ---------------------------------------------------------------------------
__global__ __launch_bounds__(256) void ranknet_pairs_kernel(
    const float* __restrict__ logits,
    const int*   __restrict__ rankings,
    float*       __restrict__ partials)
{
    const int lane = threadIdx.x & 63;
    const int wave = threadIdx.x >> 6;
    const int t = blockIdx.x * WPB + wave;   // live-tile index (wave-uniform)

    // invert t = bj*(bj+1)/2 + bi, 0 <= bi <= bj < NTILES
    int bj = (int)((__builtin_sqrtf(8.0f * (float)t + 1.0f) - 1.0f) * 0.5f);
    while ((bj + 1) * (bj + 2) / 2 <= t) ++bj;   // guard fp rounding
    while (bj * (bj + 1) / 2 > t)       --bj;
    const int bi = t - bj * (bj + 1) / 2;

    const float LOG2E = 1.4426950408889634f;
    const float INF   = __builtin_inff();

    // i-side per-lane values; j-side register copy (one element per lane)
    const float lis = logits[bi * TILE + lane] * LOG2E;
    const float ri  = (float)rankings[bi * TILE + lane];
    const float ljv = logits[bj * TILE + lane] * LOG2E;
    const float rjv = (float)rankings[bj * TILE + lane];

    float acc0 = 0.0f, acc1 = 0.0f, acc2 = 0.0f, acc3 = 0.0f;

    if (bi != bj) {
        // off-diagonal: i < j for every pair
        #pragma unroll
        for (int jj = 0; jj < TILE; jj += 4) {
            const float lj0 = readlane_f(ljv, jj    ), rj0 = readlane_f(rjv, jj    );
            const float lj1 = readlane_f(ljv, jj + 1), rj1 = readlane_f(rjv, jj + 1);
            const float lj2 = readlane_f(ljv, jj + 2), rj2 = readlane_f(rjv, jj + 2);
            const float lj3 = readlane_f(ljv, jj + 3), rj3 = readlane_f(rjv, jj + 3);

            const float sp0 = __builtin_amdgcn_logf(1.0f + __builtin_amdgcn_exp2f(lj0 - lis));
            const float sp1 = __builtin_amdgcn_logf(1.0f + __builtin_amdgcn_exp2f(lj1 - lis));
            const float sp2 = __builtin_amdgcn_logf(1.0f + __builtin_amdgcn_exp2f(lj2 - lis));
            const float sp3 = __builtin_amdgcn_logf(1.0f + __builtin_amdgcn_exp2f(lj3 - lis));

            const float rs0 = (rj0 > ri) ? (ri + rj0) : INF;  // rcp(inf)=0 masks
            const float rs1 = (rj1 > ri) ? (ri + rj1) : INF;
            const float rs2 = (rj2 > ri) ? (ri + rj2) : INF;
            const float rs3 = (rj3 > ri) ? (ri + rj3) : INF;

            acc0 = fmaf(__builtin_amdgcn_rcpf(rs0), sp0, acc0);
            acc1 = fmaf(__builtin_amdgcn_rcpf(rs1), sp1, acc1);
            acc2 = fmaf(__builtin_amdgcn_rcpf(rs2), sp2, acc2);
            acc3 = fmaf(__builtin_amdgcn_rcpf(rs3), sp3, acc3);
        }
    } else {
        // diagonal tile: also require j > i (jj > lane)
        #pragma unroll
        for (int jj = 0; jj < TILE; jj += 4) {
            const float lj0 = readlane_f(ljv, jj    ), rj0 = readlane_f(rjv, jj    );
            const float lj1 = readlane_f(ljv, jj + 1), rj1 = readlane_f(rjv, jj + 1);
            const float lj2 = readlane_f(ljv, jj + 2), rj2 = readlane_f(rjv, jj + 2);
            const float lj3 = readlane_f(ljv, jj + 3), rj3 = readlane_f(rjv, jj + 3);

            const float sp0 = __builtin_amdgcn_logf(1.0f + __builtin_amdgcn_exp2f(lj0 - lis));
            const float sp1 = __builtin_amdgcn_logf(1.0f + __builtin_amdgcn_exp2f(lj1 - lis));
            const float sp2 = __builtin_amdgcn_logf(1.0f + __builtin_amdgcn_exp2f(lj2 - lis));
            const float sp3 = __builtin_amdgcn_logf(1.0f + __builtin_amdgcn_exp2f(lj3 - lis));

            const float rs0 = ((jj     > lane) && (rj0 > ri)) ? (ri + rj0) : INF;
            const float rs1 = ((jj + 1 > lane) && (rj1 > ri)) ? (ri + rj1) : INF;
            const float rs2 = ((jj + 2 > lane) && (rj2 > ri)) ? (ri + rj2) : INF;
            const float rs3 = ((jj + 3 > lane) && (rj3 > ri)) ? (ri + rj3) : INF;

            acc0 = fmaf(__builtin_amdgcn_rcpf(rs0), sp0, acc0);
            acc1 = fmaf(__builtin_amdgcn_rcpf(rs1), sp1, acc1);
            acc2 = fmaf(__builtin_amdgcn_rcpf(rs2), sp2, acc2);
            acc3 = fmaf(__builtin_amdgcn_rcpf(rs3), sp3, acc3);
        }
    }

    // per-wave reduction — no LDS, no barrier
    float acc = (acc0 + acc1) + (acc2 + acc3);
    #pragma unroll
    for (int off = 32; off > 0; off >>= 1)
        acc += __shfl_down(acc, off, 64);
    if (lane == 0)
        partials[t] = acc;
}

// ---------------------------------------------------------------------------
// Pass 2: one 1024-thread block reduces the NLIVE partials; applies ln2/N.
// ---------------------------------------------------------------------------
__global__ __launch_bounds__(1024) void ranknet_reduce_kernel(
    const float* __restrict__ partials,
    float*       __restrict__ out)
{
    __shared__ float s_part[16];
    const int tid = threadIdx.x;

    float acc = 0.0f;
    for (int k = tid; k < NLIVE; k += 1024)
        acc += partials[k];

    #pragma unroll
    for (int off = 32; off > 0; off >>= 1)
        acc += __shfl_down(acc, off, 64);
    if ((tid & 63) == 0) s_part[tid >> 6] = acc;
    __syncthreads();
    if (tid == 0) {
        float s = 0.0f;
        #pragma unroll
        for (int w = 0; w < 16; ++w) s += s_part[w];
        const float LN2 = 0.6931471805599453f;
        out[0] = s * (LN2 / (float)N_CAND);
    }
}

extern "C" void kernel_launch(void* const* d_in, const int* in_sizes, int n_in,
                              void* d_out, int out_size, void* d_ws, size_t ws_size,
                              hipStream_t stream)
{
    const float* logits   = (const float*)d_in[0];
    const int*   rankings = (const int*)  d_in[1];
    float*       out      = (float*)d_out;
    float*       partials = (float*)d_ws;   // NLIVE floats = 33 KB

    ranknet_pairs_kernel<<<dim3(NBLK), dim3(256), 0, stream>>>(logits, rankings, partials);
    ranknet_reduce_kernel<<<1, 1024, 0, stream>>>(partials, out);
}